// Round 8
// baseline (620.145 us; speedup 1.0000x reference)
//
#include <hip/hip_runtime.h>

typedef _Float16 half_t;
typedef _Float16 half2_t __attribute__((ext_vector_type(2)));
union pk_u { unsigned int u; half2_t h; };

// ext_vector aliases: __builtin_nontemporal_* requires scalar/ext-vector types
typedef unsigned int u32x2 __attribute__((ext_vector_type(2)));
typedef int          i32x2 __attribute__((ext_vector_type(2)));
typedef float        f32x4 __attribute__((ext_vector_type(4)));

#define EMB 64
#define NLAYERS 3
#define BSH2 8
#define BW2 256            // nodes per coarse bucket
#define NB2MAX 1024        // max bucket count (N<=262144)
#define GSPREAD 32         // gcount: one counter per 128-B line
#define CAP 10240          // tmp region per bucket (avg 8533 edges, +20%)
#define EGCAP 16384        // eg region per bucket: 32-padded lists (avg ~12.6K) + slack
#define P1_BATCH 4096
#define P1_TH 512
#define P1_EPT 8           // edges per thread in part_kernel (4096/512)
#define BINTH 512

// ---- register-only inclusive scan within a 64-lane wave ----
__device__ inline int wave_incl_scan(int v) {
    #pragma unroll
    for (int off = 1; off < 64; off <<= 1) {
        int u = __shfl_up(v, off);
        if ((threadIdx.x & 63) >= off) v += u;
    }
    return v;
}

// ---- 1024-entry exclusive scan, 512 threads (2 entries each), 2 barriers ----
__device__ inline void scan1024(const int* __restrict__ in, int* __restrict__ lstart,
                                int* __restrict__ wsum) {
    int t = threadIdx.x;
    int a0 = in[2 * t], a1 = in[2 * t + 1];
    int ps = a0 + a1;
    int v = wave_incl_scan(ps);
    if ((t & 63) == 63) wsum[t >> 6] = v;
    __syncthreads();
    int wid = t >> 6;
    int base = 0;
    #pragma unroll
    for (int w = 0; w < 7; ++w) base += (w < wid) ? wsum[w] : 0;
    int excl = base + v - ps;
    lstart[2 * t]     = excl;
    lstart[2 * t + 1] = excl + a0;
    __syncthreads();
}

// ---- 256-entry exclusive scan, first 256 of 512 threads, 2 barriers ----
__device__ inline void scan256(const int* __restrict__ in, int* __restrict__ lstart,
                               int* __restrict__ wsum) {
    int t = threadIdx.x;
    int v = 0, orig = 0;
    if (t < 256) {                       // waves 0-3 fully active: shfl is safe
        orig = in[t];
        v = wave_incl_scan(orig);
        if ((t & 63) == 63) wsum[t >> 6] = v;
    }
    __syncthreads();
    if (t < 256) {
        int wid = t >> 6;
        int base = 0;
        #pragma unroll
        for (int w = 0; w < 3; ++w) base += (w < wid) ? wsum[w] : 0;
        lstart[t] = base + v - orig;
    }
    __syncthreads();
}

// ---- pass 1: partition edges into 256-node buckets, LDS-sorted dense writes ----
// record = (row<<8)|(col&255)
__global__ __launch_bounds__(512) void part_kernel(
        const int* __restrict__ row, const int* __restrict__ col,
        int* __restrict__ gcount, int* __restrict__ tmp, int E, int nb2) {
    __shared__ int hist[NB2MAX];
    __shared__ int lstart[NB2MAX];
    __shared__ int gbase[NB2MAX];
    __shared__ int wsum[8];
    __shared__ int srec[P1_BATCH];
    __shared__ unsigned short sbuck[P1_BATCH];

    int base = blockIdx.x * P1_BATCH;
    int nE = min(P1_BATCH, E - base);

    for (int i = threadIdx.x; i < NB2MAX; i += P1_TH) hist[i] = 0;
    __syncthreads();

    int myc[P1_EPT];
    #pragma unroll
    for (int k = 0; k < P1_EPT; ++k) {
        int idx = base + (k << 9) + threadIdx.x;
        int c = (idx < E) ? __builtin_nontemporal_load(&col[idx]) : -1;
        myc[k] = c;
        if (c >= 0) atomicAdd(&hist[c >> BSH2], 1);
    }
    __syncthreads();

    scan1024(hist, lstart, wsum);

    for (int b = threadIdx.x; b < nb2; b += P1_TH) {
        int c = hist[b];
        int off = 0;
        if (c > 0) off = atomicAdd(&gcount[b * GSPREAD], c);
        gbase[b] = b * CAP + off - lstart[b];
    }
    __syncthreads();
    for (int b = threadIdx.x; b < NB2MAX; b += P1_TH) hist[b] = lstart[b];
    __syncthreads();

    #pragma unroll
    for (int k = 0; k < P1_EPT; ++k) {
        int idx = base + (k << 9) + threadIdx.x;
        if (idx < E) {
            int c = myc[k];
            int b = c >> BSH2;
            int r = __builtin_nontemporal_load(&row[idx]);
            int pos = atomicAdd(&hist[b], 1);
            srec[pos] = (r << BSH2) | (c & (BW2 - 1));
            sbuck[pos] = (unsigned short)b;
        }
    }
    __syncthreads();

    for (int i = threadIdx.x; i < nE; i += P1_TH)
        __builtin_nontemporal_store(srec[i], &tmp[gbase[sbuck[i]] + i]);
}

// ---- pass 2: one block per 256-node bucket. SINGLE global read of tmp:
//      stage records into LDS (40 KB) while building the dst histogram, then
//      scan + scatter from LDS into the ZERO-PADDED eg (x32 lists, sentinel
//      row N, byte offsets <<7). Fused s0 init (s0 = fp16(dis*x)) and the
//      sentinel zero rows for both fp16 tables (block 0). ----
__global__ __launch_bounds__(512) void bin_kernel(
        const int* __restrict__ tmp, const int* __restrict__ gcount,
        int* __restrict__ eg, int2* __restrict__ sd, float* __restrict__ dis,
        const float4* __restrict__ uev, const float4* __restrict__ mev,
        uint2* __restrict__ s0v, uint2* __restrict__ sbz,
        int n_users, int N) {
    __shared__ int srec[CAP];        // 40 KB staged records
    __shared__ int hist[BW2];
    __shared__ int padh[BW2];
    __shared__ int lstart[BW2];
    __shared__ int wsum[4];
    __shared__ float sdis[BW2];
    int b = blockIdx.x;
    int cnt = gcount[b * GSPREAD];
    int rbase = b * CAP;             // tmp region
    int ebase = b * EGCAP;           // eg region (padded)
    int c0 = b << BSH2;
    int nc = min(BW2, N - c0);
    int sent = N << 7;               // sentinel: byte offset of zero row

    for (int i = threadIdx.x; i < BW2; i += BINTH) hist[i] = 0;
    __syncthreads();

    // ONE global pass: stage to LDS + dst histogram
    for (int i = threadIdx.x; i < cnt; i += BINTH) {
        int rec = __builtin_nontemporal_load(&tmp[rbase + i]);
        srec[i] = rec;
        atomicAdd(&hist[rec & (BW2 - 1)], 1);
    }
    __syncthreads();

    // padded counts (multiple of 32)
    for (int c = threadIdx.x; c < BW2; c += BINTH)
        padh[c] = (hist[c] + 31) & ~31;
    __syncthreads();

    scan256(padh, lstart, wsum);     // prefix over padded counts

    // per-node metadata: sd = (padded start, padded count), dis = rsqrt(true deg)
    for (int c = threadIdx.x; c < nc; c += BINTH) {
        int d = hist[c];
        float dn = (d > 0) ? rsqrtf((float)d) : 0.0f;
        sd[c0 + c] = make_int2(ebase + lstart[c], padh[c]);
        dis[c0 + c] = dn;
        sdis[c] = dn;
    }
    __syncthreads();
    for (int i = threadIdx.x; i < BW2; i += BINTH) hist[i] = lstart[i];  // cursors
    __syncthreads();

    // scatter src byte-offsets (src*128) from LDS
    for (int i = threadIdx.x; i < cnt; i += BINTH) {
        int v = srec[i];
        int pos = atomicAdd(&hist[v & (BW2 - 1)], 1);
        __builtin_nontemporal_store((v >> BSH2) << 7, &eg[ebase + pos]);
    }
    __syncthreads();

    // pad-fill: cursor = lstart+deg; fill up to lstart+padh (<32/node) with sentinel
    for (int i = threadIdx.x; i < BW2 * 32; i += BINTH) {
        int c = i >> 5;
        int o = i & 31;
        int st = hist[c];
        int en = lstart[c] + padh[c];
        if (st + o < en) __builtin_nontemporal_store(sent, &eg[ebase + st + o]);
    }
    // 64 slack slots after the last list (covers the gather's 2-deep prefetch)
    int tot = lstart[BW2 - 1] + padh[BW2 - 1];
    if (threadIdx.x < 64)
        __builtin_nontemporal_store(sent, &eg[ebase + tot + threadIdx.x]);

    // sentinel zero rows for both fp16 tables (replaces two memsets)
    if (b == 0 && threadIdx.x < 32) {
        int q = threadIdx.x & 15;
        uint2 z = make_uint2(0u, 0u);
        if (threadIdx.x < 16) s0v[(long long)N * 16 + q] = z;
        else                  sbz[(long long)N * 16 + q] = z;
    }

    // fused s0 init for this bucket's nodes: s0 = fp16(dis*x)
    for (int i = threadIdx.x; i < nc * 16; i += BINTH) {
        int loc = i >> 4;
        int node = c0 + loc;
        int q = i & 15;
        const float4* src = (node < n_users) ? (uev + (long long)node * 16)
                                             : (mev + (long long)(node - n_users) * 16);
        f32x4 v = __builtin_nontemporal_load((const f32x4*)&src[q]);
        float dn = sdis[loc];
        pk_u w0, w1;
        w0.h[0] = (half_t)(v.x * dn); w0.h[1] = (half_t)(v.y * dn);
        w1.h[0] = (half_t)(v.z * dn); w1.h[1] = (half_t)(v.w * dn);
        u32x2 w; w.x = w0.u; w.y = w1.u;
        __builtin_nontemporal_store(w, (u32x2*)&s0v[(long long)node * 16 + q]);
    }
}

// ---------------- pull propagate: 8 lanes/row (dwordx4), 8 edge phases --------
// (round-4 proven structure: 94.1 us/layer = bytes/3.85 TB/s wall)
// All STREAM accesses (eg, sd, sOut/uOut, u1/u2, x, out) are nontemporal so
// they stop evicting the fp16 table from L2; table loads stay cached.
// lane l: p=l&7 owns dims 8p..8p+7 (one uint4/row); h=l>>3 owns edge (j+8k+h).
// Lists zero-padded to x32 (sentinel row N = zeros): branch-free, predicate-free.
// LAYER 1: reads s0, writes s1 + u1=fp16(a1) (u1 stride-16 rows, aliases tmp)
// LAYER 2: reads s1, writes s2 + u2=fp16(a2) (u2 stride-32 rows, lives in out)
// LAYER 3: reads s2 + x + u1 + u2, writes out = (x+u1+u2+a3)/4
template <int LAYER>
__global__ __launch_bounds__(256) void gather_kernel(
        const int* __restrict__ eg, const int2* __restrict__ sd,
        const float* __restrict__ dis,
        const uint4* __restrict__ tab, uint2* __restrict__ sOut,
        uint2* __restrict__ uOut,
        const uint2* __restrict__ u1, const uint2* __restrict__ u2,
        const float4* __restrict__ uev, const float4* __restrict__ mev,
        float4* __restrict__ outv, int n_users, int N) {
    int wave = blockIdx.x * (blockDim.x >> 6) + (threadIdx.x >> 6);
    if (wave >= N) return;
    int l = threadIdx.x & 63;
    int p = l & 7;
    int h = l >> 3;
    unsigned pb = (unsigned)p << 4;          // byte offset of this lane's uint4
    const char* tb = (const char*)tab;

    i32x2 se = __builtin_nontemporal_load((const i32x2*)&sd[wave]);
    int j = se.x;
    int e = se.x + se.y;                     // se.y = padded count (x32)
    pk_u a0, a1, a2, a3;
    a0.u = 0; a1.u = 0; a2.u = 0; a3.u = 0;

    if (j < e) {
        int r0 = __builtin_nontemporal_load(&eg[j + h]);
        int r1 = __builtin_nontemporal_load(&eg[j + 8 + h]);
        int r2 = __builtin_nontemporal_load(&eg[j + 16 + h]);
        int r3 = __builtin_nontemporal_load(&eg[j + 24 + h]);
        for (; j < e; j += 32) {
            int n0 = __builtin_nontemporal_load(&eg[j + 32 + h]);  // slack-safe
            int n1 = __builtin_nontemporal_load(&eg[j + 40 + h]);
            int n2 = __builtin_nontemporal_load(&eg[j + 48 + h]);
            int n3 = __builtin_nontemporal_load(&eg[j + 56 + h]);
            // eg stores src*128 (byte offset); + pb = this lane's uint4 (CACHED)
            uint4 v0 = *(const uint4*)(tb + ((unsigned)r0 + pb));
            uint4 v1 = *(const uint4*)(tb + ((unsigned)r1 + pb));
            uint4 v2 = *(const uint4*)(tb + ((unsigned)r2 + pb));
            uint4 v3 = *(const uint4*)(tb + ((unsigned)r3 + pb));
            pk_u t;
            t.u = v0.x; a0.h += t.h; t.u = v0.y; a1.h += t.h;
            t.u = v0.z; a2.h += t.h; t.u = v0.w; a3.h += t.h;
            t.u = v1.x; a0.h += t.h; t.u = v1.y; a1.h += t.h;
            t.u = v1.z; a2.h += t.h; t.u = v1.w; a3.h += t.h;
            t.u = v2.x; a0.h += t.h; t.u = v2.y; a1.h += t.h;
            t.u = v2.z; a2.h += t.h; t.u = v2.w; a3.h += t.h;
            t.u = v3.x; a0.h += t.h; t.u = v3.y; a1.h += t.h;
            t.u = v3.z; a2.h += t.h; t.u = v3.w; a3.h += t.h;
            r0 = n0; r1 = n1; r2 = n2; r3 = n3;
        }
    }

    // reduce across the 8 edge-phases (packed); all lanes end with full sums
    #pragma unroll
    for (int m = 8; m <= 32; m <<= 1) {
        pk_u t;
        t.u = (unsigned int)__shfl_xor((int)a0.u, m); a0.h += t.h;
        t.u = (unsigned int)__shfl_xor((int)a1.u, m); a1.h += t.h;
        t.u = (unsigned int)__shfl_xor((int)a2.u, m); a2.h += t.h;
        t.u = (unsigned int)__shfl_xor((int)a3.u, m); a3.h += t.h;
    }

    if (h < 2) {                             // 16 lanes handle the 64-dim row
        pk_u x0 = h ? a2 : a0;
        pk_u x1 = h ? a3 : a1;
        float dc = dis[wave];
        float g0 = dc * (float)x0.h[0];
        float g1 = dc * (float)x0.h[1];
        float g2 = dc * (float)x1.h[0];
        float g3 = dc * (float)x1.h[1];
        int q = p * 2 + h;
        long long o16 = (long long)wave * 16 + q;
        if (LAYER < 3) {
            pk_u w0, w1, uw0, uw1;
            w0.h[0] = (half_t)(dc * g0); w0.h[1] = (half_t)(dc * g1);
            w1.h[0] = (half_t)(dc * g2); w1.h[1] = (half_t)(dc * g3);
            uw0.h[0] = (half_t)g0; uw0.h[1] = (half_t)g1;
            uw1.h[0] = (half_t)g2; uw1.h[1] = (half_t)g3;
            u32x2 wa; wa.x = w0.u; wa.y = w1.u;
            u32x2 wb; wb.x = uw0.u; wb.y = uw1.u;
            __builtin_nontemporal_store(wa, (u32x2*)&sOut[o16]);
            long long uo = (LAYER == 1) ? o16 : ((long long)wave * 32 + q);
            __builtin_nontemporal_store(wb, (u32x2*)&uOut[uo]);
        } else {
            const float4* src = (wave < n_users) ? (uev + (long long)wave * 16)
                                                 : (mev + (long long)(wave - n_users) * 16);
            f32x4 xv = __builtin_nontemporal_load((const f32x4*)&src[q]);
            u32x2 ua2 = __builtin_nontemporal_load((const u32x2*)&u1[o16]);
            u32x2 ub2 = __builtin_nontemporal_load(
                (const u32x2*)&u2[(long long)wave * 32 + q]);
            pk_u pa, pb2, pc, pd;
            pa.u = ua2.x; pb2.u = ua2.y; pc.u = ub2.x; pd.u = ub2.y;
            f32x4 r;
            r.x = (xv.x + (float)pa.h[0]  + (float)pc.h[0] + g0) * 0.25f;
            r.y = (xv.y + (float)pa.h[1]  + (float)pc.h[1] + g1) * 0.25f;
            r.z = (xv.z + (float)pb2.h[0] + (float)pd.h[0] + g2) * 0.25f;
            r.w = (xv.w + (float)pb2.h[1] + (float)pd.h[1] + g3) * 0.25f;
            // same-row in-place over u2: per-lane data dep (r uses ub2) orders
            // the load before the store
            __builtin_nontemporal_store(r, (f32x4*)&outv[o16]);
        }
    }
}

extern "C" void kernel_launch(void* const* d_in, const int* in_sizes, int n_in,
                              void* d_out, int out_size, void* d_ws, size_t ws_size,
                              hipStream_t stream) {
    const int*   edge = (const int*)d_in[0];    // [2, E]: row then col
    const float* ue   = (const float*)d_in[2];
    const float* me   = (const float*)d_in[3];
    float*       out  = (float*)d_out;

    const int E        = in_sizes[0] / 2;
    const int n_users  = in_sizes[2] / EMB;
    const int n_movies = in_sizes[3] / EMB;
    const int N        = n_users + n_movies;
    const int* row = edge;
    const int* col = edge + E;
    const int nb2 = (N + BW2 - 1) >> BSH2;      // 586 coarse buckets

    // workspace layout
    char* ws = (char*)d_ws;
    auto align_up = [](size_t v) { return (v + 255) & ~(size_t)255; };
    int*    gcount = (int*)ws;    ws += align_up((size_t)NB2MAX * GSPREAD * sizeof(int));
    int2*   sd     = (int2*)ws;   ws += align_up((size_t)N * sizeof(int2));
    float*  dis    = (float*)ws;  ws += align_up((size_t)N * sizeof(float));
    int*    tmp    = (int*)ws;    ws += align_up((size_t)nb2 * CAP * sizeof(int));
    int*    eg     = (int*)ws;    ws += align_up((size_t)nb2 * EGCAP * sizeof(int));
    half_t* sA     = (half_t*)ws; ws += align_up((size_t)(N + 1) * EMB * sizeof(half_t));
    half_t* sB     = (half_t*)ws; ws += align_up((size_t)(N + 1) * EMB * sizeof(half_t));
    // u1 = fp16(a1), stride-16 rows: aliases tmp (dead after bin_kernel; 19.2<=24MB)
    uint2* u1 = (uint2*)tmp;
    // u2 = fp16(a2), stride-32 rows: lives in the (unwritten) out buffer
    uint2* u2 = (uint2*)out;

    // two-pass counting sort -> padded CSR (deg/dis/s0/zero-rows fused in pass 2)
    hipMemsetAsync(gcount, 0, (size_t)NB2MAX * GSPREAD * sizeof(int), stream);
    part_kernel<<<(E + P1_BATCH - 1) / P1_BATCH, P1_TH, 0, stream>>>(
        row, col, gcount, tmp, E, nb2);
    bin_kernel<<<nb2, BINTH, 0, stream>>>(
        tmp, gcount, eg, sd, dis,
        (const float4*)ue, (const float4*)me, (uint2*)sA, (uint2*)sB,
        n_users, N);

    // 3 propagation layers (atomic-free pull, packed fp16, no out RMW)
    const int waves_per_block = 4;   // 256 threads
    const int gblocks = (N + waves_per_block - 1) / waves_per_block;
    gather_kernel<1><<<gblocks, 256, 0, stream>>>(
        eg, sd, dis, (const uint4*)sA, (uint2*)sB, u1,
        nullptr, nullptr, nullptr, nullptr, nullptr, n_users, N);
    gather_kernel<2><<<gblocks, 256, 0, stream>>>(
        eg, sd, dis, (const uint4*)sB, (uint2*)sA, u2,
        nullptr, nullptr, nullptr, nullptr, nullptr, n_users, N);
    gather_kernel<3><<<gblocks, 256, 0, stream>>>(
        eg, sd, dis, (const uint4*)sA, nullptr, nullptr,
        (const uint2*)u1, (const uint2*)u2,
        (const float4*)ue, (const float4*)me, (float4*)out, n_users, N);
}

// Round 9
// 472.047 us; speedup vs baseline: 1.3137x; 1.3137x over previous
//
#include <hip/hip_runtime.h>

typedef _Float16 half_t;
typedef _Float16 half2_t __attribute__((ext_vector_type(2)));
union pk_u { unsigned int u; half2_t h; };

#define EMB 64
#define NLAYERS 3
#define BSH2 8
#define BW2 256            // nodes per coarse bucket
#define NB2MAX 1024        // max bucket count (N<=262144)
#define GSPREAD 32         // gcount: one counter per 128-B line
#define CAP 10240          // tmp region per bucket (avg 8533 edges, +20%)
#define EGCAP 16384        // eg region per bucket: 32-padded lists (avg ~12.6K) + slack
#define P1_BATCH 4096
#define P1_TH 512
#define P1_EPT 8           // edges per thread in part_kernel (4096/512)
#define BINTH 512

// ---- register-only inclusive scan within a 64-lane wave ----
__device__ inline int wave_incl_scan(int v) {
    #pragma unroll
    for (int off = 1; off < 64; off <<= 1) {
        int u = __shfl_up(v, off);
        if ((threadIdx.x & 63) >= off) v += u;
    }
    return v;
}

// ---- 1024-entry exclusive scan, 512 threads (2 entries each), 2 barriers ----
__device__ inline void scan1024(const int* __restrict__ in, int* __restrict__ lstart,
                                int* __restrict__ wsum) {
    int t = threadIdx.x;
    int a0 = in[2 * t], a1 = in[2 * t + 1];
    int ps = a0 + a1;
    int v = wave_incl_scan(ps);
    if ((t & 63) == 63) wsum[t >> 6] = v;
    __syncthreads();
    int wid = t >> 6;
    int base = 0;
    #pragma unroll
    for (int w = 0; w < 7; ++w) base += (w < wid) ? wsum[w] : 0;
    int excl = base + v - ps;
    lstart[2 * t]     = excl;
    lstart[2 * t + 1] = excl + a0;
    __syncthreads();
}

// ---- 256-entry exclusive scan, first 256 of 512 threads, 2 barriers ----
__device__ inline void scan256(const int* __restrict__ in, int* __restrict__ lstart,
                               int* __restrict__ wsum) {
    int t = threadIdx.x;
    int v = 0, orig = 0;
    if (t < 256) {                       // waves 0-3 fully active: shfl is safe
        orig = in[t];
        v = wave_incl_scan(orig);
        if ((t & 63) == 63) wsum[t >> 6] = v;
    }
    __syncthreads();
    if (t < 256) {
        int wid = t >> 6;
        int base = 0;
        #pragma unroll
        for (int w = 0; w < 3; ++w) base += (w < wid) ? wsum[w] : 0;
        lstart[t] = base + v - orig;
    }
    __syncthreads();
}

// ---- pass 1: partition edges into 256-node buckets, LDS-sorted dense writes ----
// record = (row<<8)|(col&255)
__global__ __launch_bounds__(512) void part_kernel(
        const int* __restrict__ row, const int* __restrict__ col,
        int* __restrict__ gcount, int* __restrict__ tmp, int E, int nb2) {
    __shared__ int hist[NB2MAX];
    __shared__ int lstart[NB2MAX];
    __shared__ int gbase[NB2MAX];
    __shared__ int wsum[8];
    __shared__ int srec[P1_BATCH];
    __shared__ unsigned short sbuck[P1_BATCH];

    int base = blockIdx.x * P1_BATCH;
    int nE = min(P1_BATCH, E - base);

    for (int i = threadIdx.x; i < NB2MAX; i += P1_TH) hist[i] = 0;
    __syncthreads();

    int myc[P1_EPT];
    #pragma unroll
    for (int k = 0; k < P1_EPT; ++k) {
        int idx = base + (k << 9) + threadIdx.x;
        int c = (idx < E) ? col[idx] : -1;
        myc[k] = c;
        if (c >= 0) atomicAdd(&hist[c >> BSH2], 1);
    }
    __syncthreads();

    scan1024(hist, lstart, wsum);

    for (int b = threadIdx.x; b < nb2; b += P1_TH) {
        int c = hist[b];
        int off = 0;
        if (c > 0) off = atomicAdd(&gcount[b * GSPREAD], c);
        gbase[b] = b * CAP + off - lstart[b];
    }
    __syncthreads();
    for (int b = threadIdx.x; b < NB2MAX; b += P1_TH) hist[b] = lstart[b];
    __syncthreads();

    #pragma unroll
    for (int k = 0; k < P1_EPT; ++k) {
        int idx = base + (k << 9) + threadIdx.x;
        if (idx < E) {
            int c = myc[k];
            int b = c >> BSH2;
            int r = row[idx];
            int pos = atomicAdd(&hist[b], 1);
            srec[pos] = (r << BSH2) | (c & (BW2 - 1));
            sbuck[pos] = (unsigned short)b;
        }
    }
    __syncthreads();

    for (int i = threadIdx.x; i < nE; i += P1_TH)
        tmp[gbase[sbuck[i]] + i] = srec[i];
}

// ---- pass 2: one block per 256-node bucket. SINGLE global read of tmp:
//      stage records into LDS (40 KB) while building the dst histogram, then
//      scan + scatter from LDS into the ZERO-PADDED eg (x32 lists, sentinel
//      row N, byte offsets <<7). Fused s0 init (s0 = fp16(dis*x)) and the
//      sentinel zero rows for both fp16 tables (block 0). ----
__global__ __launch_bounds__(512) void bin_kernel(
        const int* __restrict__ tmp, const int* __restrict__ gcount,
        int* __restrict__ eg, int2* __restrict__ sd, float* __restrict__ dis,
        const float4* __restrict__ uev, const float4* __restrict__ mev,
        uint2* __restrict__ s0v, uint2* __restrict__ sbz,
        int n_users, int N) {
    __shared__ int srec[CAP];        // 40 KB staged records
    __shared__ int hist[BW2];
    __shared__ int padh[BW2];
    __shared__ int lstart[BW2];
    __shared__ int wsum[4];
    __shared__ float sdis[BW2];
    int b = blockIdx.x;
    int cnt = gcount[b * GSPREAD];
    int rbase = b * CAP;             // tmp region
    int ebase = b * EGCAP;           // eg region (padded)
    int c0 = b << BSH2;
    int nc = min(BW2, N - c0);
    int sent = N << 7;               // sentinel: byte offset of zero row

    for (int i = threadIdx.x; i < BW2; i += BINTH) hist[i] = 0;
    __syncthreads();

    // ONE global pass: stage to LDS + dst histogram
    for (int i = threadIdx.x; i < cnt; i += BINTH) {
        int rec = tmp[rbase + i];
        srec[i] = rec;
        atomicAdd(&hist[rec & (BW2 - 1)], 1);
    }
    __syncthreads();

    // padded counts (multiple of 32)
    for (int c = threadIdx.x; c < BW2; c += BINTH)
        padh[c] = (hist[c] + 31) & ~31;
    __syncthreads();

    scan256(padh, lstart, wsum);     // prefix over padded counts

    // per-node metadata: sd = (padded start, padded count), dis = rsqrt(true deg)
    for (int c = threadIdx.x; c < nc; c += BINTH) {
        int d = hist[c];
        float dn = (d > 0) ? rsqrtf((float)d) : 0.0f;
        sd[c0 + c] = make_int2(ebase + lstart[c], padh[c]);
        dis[c0 + c] = dn;
        sdis[c] = dn;
    }
    __syncthreads();
    for (int i = threadIdx.x; i < BW2; i += BINTH) hist[i] = lstart[i];  // cursors
    __syncthreads();

    // scatter src byte-offsets (src*128) from LDS
    for (int i = threadIdx.x; i < cnt; i += BINTH) {
        int v = srec[i];
        int pos = atomicAdd(&hist[v & (BW2 - 1)], 1);
        eg[ebase + pos] = (v >> BSH2) << 7;
    }
    __syncthreads();

    // pad-fill: cursor = lstart+deg; fill up to lstart+padh (<32/node) with sentinel
    for (int i = threadIdx.x; i < BW2 * 32; i += BINTH) {
        int c = i >> 5;
        int o = i & 31;
        int st = hist[c];
        int en = lstart[c] + padh[c];
        if (st + o < en) eg[ebase + st + o] = sent;
    }
    // 64 slack slots after the last list (covers the gather's 2-deep prefetch)
    int tot = lstart[BW2 - 1] + padh[BW2 - 1];
    if (threadIdx.x < 64) eg[ebase + tot + threadIdx.x] = sent;

    // sentinel zero rows for both fp16 tables (replaces two memsets)
    if (b == 0 && threadIdx.x < 32) {
        int q = threadIdx.x & 15;
        uint2 z = make_uint2(0u, 0u);
        if (threadIdx.x < 16) s0v[(long long)N * 16 + q] = z;
        else                  sbz[(long long)N * 16 + q] = z;
    }

    // fused s0 init for this bucket's nodes: s0 = fp16(dis*x)
    for (int i = threadIdx.x; i < nc * 16; i += BINTH) {
        int loc = i >> 4;
        int node = c0 + loc;
        int q = i & 15;
        const float4* src = (node < n_users) ? (uev + (long long)node * 16)
                                             : (mev + (long long)(node - n_users) * 16);
        float4 v = src[q];
        float dn = sdis[loc];
        pk_u w0, w1;
        w0.h[0] = (half_t)(v.x * dn); w0.h[1] = (half_t)(v.y * dn);
        w1.h[0] = (half_t)(v.z * dn); w1.h[1] = (half_t)(v.w * dn);
        s0v[(long long)node * 16 + q] = make_uint2(w0.u, w1.u);
    }
}

// ---------------- pull propagate: 8 lanes/row (dwordx4), 8 edge phases --------
// (round-4/6 proven structure: 94.1 us/layer = bytes/3.85 TB/s wall)
// lane l: p=l&7 owns dims 8p..8p+7 (one uint4/row); h=l>>3 owns edge (j+8k+h).
// Lists zero-padded to x32 (sentinel row N = zeros): branch-free, predicate-free.
// 2-deep eg prefetch (safe via 64 sentinel slack slots per bucket).
// LAYER 1: reads s0, writes s1 + u1=fp16(a1) (u1 stride-16 rows, aliases tmp)
// LAYER 2: reads s1, writes s2 + u2=fp16(a2) (u2 stride-32 rows, lives in out)
// LAYER 3: reads s2 + x + u1 + u2, writes out = (x+u1+u2+a3)/4
template <int LAYER>
__global__ __launch_bounds__(256) void gather_kernel(
        const int* __restrict__ eg, const int2* __restrict__ sd,
        const float* __restrict__ dis,
        const uint4* __restrict__ tab, uint2* __restrict__ sOut,
        uint2* __restrict__ uOut,
        const uint2* __restrict__ u1, const uint2* __restrict__ u2,
        const float4* __restrict__ uev, const float4* __restrict__ mev,
        float4* __restrict__ outv, int n_users, int N) {
    int wave = blockIdx.x * (blockDim.x >> 6) + (threadIdx.x >> 6);
    if (wave >= N) return;
    int l = threadIdx.x & 63;
    int p = l & 7;
    int h = l >> 3;
    unsigned pb = (unsigned)p << 4;          // byte offset of this lane's uint4
    const char* tb = (const char*)tab;

    int2 se = sd[wave];
    int j = se.x;
    int e = se.x + se.y;                     // se.y = padded count (x32)
    pk_u a0, a1, a2, a3;
    a0.u = 0; a1.u = 0; a2.u = 0; a3.u = 0;

    if (j < e) {
        int r0 = eg[j + h];
        int r1 = eg[j + 8 + h];
        int r2 = eg[j + 16 + h];
        int r3 = eg[j + 24 + h];
        for (; j < e; j += 32) {
            int n0 = eg[j + 32 + h];         // prefetch next chunk (slack-safe)
            int n1 = eg[j + 40 + h];
            int n2 = eg[j + 48 + h];
            int n3 = eg[j + 56 + h];
            // eg stores src*128 (byte offset); + pb = this lane's uint4
            uint4 v0 = *(const uint4*)(tb + ((unsigned)r0 + pb));
            uint4 v1 = *(const uint4*)(tb + ((unsigned)r1 + pb));
            uint4 v2 = *(const uint4*)(tb + ((unsigned)r2 + pb));
            uint4 v3 = *(const uint4*)(tb + ((unsigned)r3 + pb));
            pk_u t;
            t.u = v0.x; a0.h += t.h; t.u = v0.y; a1.h += t.h;
            t.u = v0.z; a2.h += t.h; t.u = v0.w; a3.h += t.h;
            t.u = v1.x; a0.h += t.h; t.u = v1.y; a1.h += t.h;
            t.u = v1.z; a2.h += t.h; t.u = v1.w; a3.h += t.h;
            t.u = v2.x; a0.h += t.h; t.u = v2.y; a1.h += t.h;
            t.u = v2.z; a2.h += t.h; t.u = v2.w; a3.h += t.h;
            t.u = v3.x; a0.h += t.h; t.u = v3.y; a1.h += t.h;
            t.u = v3.z; a2.h += t.h; t.u = v3.w; a3.h += t.h;
            r0 = n0; r1 = n1; r2 = n2; r3 = n3;
        }
    }

    // reduce across the 8 edge-phases (packed); all lanes end with full sums
    #pragma unroll
    for (int m = 8; m <= 32; m <<= 1) {
        pk_u t;
        t.u = (unsigned int)__shfl_xor((int)a0.u, m); a0.h += t.h;
        t.u = (unsigned int)__shfl_xor((int)a1.u, m); a1.h += t.h;
        t.u = (unsigned int)__shfl_xor((int)a2.u, m); a2.h += t.h;
        t.u = (unsigned int)__shfl_xor((int)a3.u, m); a3.h += t.h;
    }

    if (h < 2) {                             // 16 lanes handle the 64-dim row
        pk_u x0 = h ? a2 : a0;
        pk_u x1 = h ? a3 : a1;
        float dc = dis[wave];
        float g0 = dc * (float)x0.h[0];
        float g1 = dc * (float)x0.h[1];
        float g2 = dc * (float)x1.h[0];
        float g3 = dc * (float)x1.h[1];
        int q = p * 2 + h;
        long long o16 = (long long)wave * 16 + q;
        if (LAYER < 3) {
            pk_u w0, w1, uw0, uw1;
            w0.h[0] = (half_t)(dc * g0); w0.h[1] = (half_t)(dc * g1);
            w1.h[0] = (half_t)(dc * g2); w1.h[1] = (half_t)(dc * g3);
            uw0.h[0] = (half_t)g0; uw0.h[1] = (half_t)g1;
            uw1.h[0] = (half_t)g2; uw1.h[1] = (half_t)g3;
            sOut[o16] = make_uint2(w0.u, w1.u);
            long long uo = (LAYER == 1) ? o16 : ((long long)wave * 32 + q);
            uOut[uo] = make_uint2(uw0.u, uw1.u);
        } else {
            const float4* src = (wave < n_users) ? (uev + (long long)wave * 16)
                                                 : (mev + (long long)(wave - n_users) * 16);
            float4 xv = src[q];
            uint2 ua2 = u1[o16];
            uint2 ub2 = u2[(long long)wave * 32 + q];
            pk_u pa, pb2, pc, pd;
            pa.u = ua2.x; pb2.u = ua2.y; pc.u = ub2.x; pd.u = ub2.y;
            float4 r;
            r.x = (xv.x + (float)pa.h[0]  + (float)pc.h[0] + g0) * 0.25f;
            r.y = (xv.y + (float)pa.h[1]  + (float)pc.h[1] + g1) * 0.25f;
            r.z = (xv.z + (float)pb2.h[0] + (float)pd.h[0] + g2) * 0.25f;
            r.w = (xv.w + (float)pb2.h[1] + (float)pd.h[1] + g3) * 0.25f;
            outv[o16] = r;                   // same-row in-place over u2: load-before-store
        }
    }
}

extern "C" void kernel_launch(void* const* d_in, const int* in_sizes, int n_in,
                              void* d_out, int out_size, void* d_ws, size_t ws_size,
                              hipStream_t stream) {
    const int*   edge = (const int*)d_in[0];    // [2, E]: row then col
    const float* ue   = (const float*)d_in[2];
    const float* me   = (const float*)d_in[3];
    float*       out  = (float*)d_out;

    const int E        = in_sizes[0] / 2;
    const int n_users  = in_sizes[2] / EMB;
    const int n_movies = in_sizes[3] / EMB;
    const int N        = n_users + n_movies;
    const int* row = edge;
    const int* col = edge + E;
    const int nb2 = (N + BW2 - 1) >> BSH2;      // 586 coarse buckets

    // workspace layout
    char* ws = (char*)d_ws;
    auto align_up = [](size_t v) { return (v + 255) & ~(size_t)255; };
    int*    gcount = (int*)ws;    ws += align_up((size_t)NB2MAX * GSPREAD * sizeof(int));
    int2*   sd     = (int2*)ws;   ws += align_up((size_t)N * sizeof(int2));
    float*  dis    = (float*)ws;  ws += align_up((size_t)N * sizeof(float));
    int*    tmp    = (int*)ws;    ws += align_up((size_t)nb2 * CAP * sizeof(int));
    int*    eg     = (int*)ws;    ws += align_up((size_t)nb2 * EGCAP * sizeof(int));
    half_t* sA     = (half_t*)ws; ws += align_up((size_t)(N + 1) * EMB * sizeof(half_t));
    half_t* sB     = (half_t*)ws; ws += align_up((size_t)(N + 1) * EMB * sizeof(half_t));
    // u1 = fp16(a1), stride-16 rows: aliases tmp (dead after bin_kernel; 19.2<=24MB)
    uint2* u1 = (uint2*)tmp;
    // u2 = fp16(a2), stride-32 rows: lives in the (unwritten) out buffer
    uint2* u2 = (uint2*)out;

    // two-pass counting sort -> padded CSR (deg/dis/s0/zero-rows fused in pass 2)
    hipMemsetAsync(gcount, 0, (size_t)NB2MAX * GSPREAD * sizeof(int), stream);
    part_kernel<<<(E + P1_BATCH - 1) / P1_BATCH, P1_TH, 0, stream>>>(
        row, col, gcount, tmp, E, nb2);
    bin_kernel<<<nb2, BINTH, 0, stream>>>(
        tmp, gcount, eg, sd, dis,
        (const float4*)ue, (const float4*)me, (uint2*)sA, (uint2*)sB,
        n_users, N);

    // 3 propagation layers (atomic-free pull, packed fp16, no out RMW)
    const int waves_per_block = 4;   // 256 threads
    const int gblocks = (N + waves_per_block - 1) / waves_per_block;
    gather_kernel<1><<<gblocks, 256, 0, stream>>>(
        eg, sd, dis, (const uint4*)sA, (uint2*)sB, u1,
        nullptr, nullptr, nullptr, nullptr, nullptr, n_users, N);
    gather_kernel<2><<<gblocks, 256, 0, stream>>>(
        eg, sd, dis, (const uint4*)sB, (uint2*)sA, u2,
        nullptr, nullptr, nullptr, nullptr, nullptr, n_users, N);
    gather_kernel<3><<<gblocks, 256, 0, stream>>>(
        eg, sd, dis, (const uint4*)sA, nullptr, nullptr,
        (const uint2*)u1, (const uint2*)u2,
        (const float4*)ue, (const float4*)me, (float4*)out, n_users, N);
}

// Round 10
// 462.267 us; speedup vs baseline: 1.3415x; 1.0212x over previous
//
#include <hip/hip_runtime.h>

typedef _Float16 half_t;
typedef _Float16 half2_t __attribute__((ext_vector_type(2)));
union pk_u { unsigned int u; half2_t h; };

#define EMB 64
#define NLAYERS 3
#define BSH2 8
#define BW2 256            // nodes per coarse bucket
#define NB2MAX 1024        // max bucket count (N<=262144)
#define GSPREAD 32         // counter stride: one counter per 128-B line
#define SUBC 8             // sub-counters per bucket (one per XCD class)
#define CAP 10240          // tmp region per bucket = SUBC * SUBCAP
#define SUBCAP 1280        // per (bucket, xcd-class) sub-region (mean 1066, +6.5 sigma)
#define EGCAP 16384        // eg region per bucket: 32-padded lists (avg ~12.6K) + slack
#define P1_BATCH 4096
#define P1_TH 512
#define P1_EPT 8           // edges per thread in part_kernel (4096/512)
#define BINTH 512

// ---- register-only inclusive scan within a 64-lane wave ----
__device__ inline int wave_incl_scan(int v) {
    #pragma unroll
    for (int off = 1; off < 64; off <<= 1) {
        int u = __shfl_up(v, off);
        if ((threadIdx.x & 63) >= off) v += u;
    }
    return v;
}

// ---- 1024-entry exclusive scan, 512 threads (2 entries each), 2 barriers ----
__device__ inline void scan1024(const int* __restrict__ in, int* __restrict__ lstart,
                                int* __restrict__ wsum) {
    int t = threadIdx.x;
    int a0 = in[2 * t], a1 = in[2 * t + 1];
    int ps = a0 + a1;
    int v = wave_incl_scan(ps);
    if ((t & 63) == 63) wsum[t >> 6] = v;
    __syncthreads();
    int wid = t >> 6;
    int base = 0;
    #pragma unroll
    for (int w = 0; w < 7; ++w) base += (w < wid) ? wsum[w] : 0;
    int excl = base + v - ps;
    lstart[2 * t]     = excl;
    lstart[2 * t + 1] = excl + a0;
    __syncthreads();
}

// ---- 256-entry exclusive scan, first 256 of 512 threads, 2 barriers ----
__device__ inline void scan256(const int* __restrict__ in, int* __restrict__ lstart,
                               int* __restrict__ wsum) {
    int t = threadIdx.x;
    int v = 0, orig = 0;
    if (t < 256) {                       // waves 0-3 fully active: shfl is safe
        orig = in[t];
        v = wave_incl_scan(orig);
        if ((t & 63) == 63) wsum[t >> 6] = v;
    }
    __syncthreads();
    if (t < 256) {
        int wid = t >> 6;
        int base = 0;
        #pragma unroll
        for (int w = 0; w < 3; ++w) base += (w < wid) ? wsum[w] : 0;
        lstart[t] = base + v - orig;
    }
    __syncthreads();
}

// ---- pass 1: partition edges into 256-node buckets, LDS-sorted dense writes ----
// record = (row<<8)|(col&255)
// gcount[(s*NB2MAX+b)*GSPREAD], s = blockIdx&7: each counter line is touched by
// ONE XCD class only (round-robin dispatch) -> no cross-XCD atomic ping-pong,
// per-line chain depth 1221 -> ~153 L2-local RMWs.
__global__ __launch_bounds__(512) void part_kernel(
        const int* __restrict__ row, const int* __restrict__ col,
        int* __restrict__ gcount, int* __restrict__ tmp, int E, int nb2) {
    __shared__ int hist[NB2MAX];
    __shared__ int lstart[NB2MAX];
    __shared__ int gbase[NB2MAX];
    __shared__ int wsum[8];
    __shared__ int srec[P1_BATCH];
    __shared__ unsigned short sbuck[P1_BATCH];

    int base = blockIdx.x * P1_BATCH;
    int nE = min(P1_BATCH, E - base);
    int s = blockIdx.x & (SUBC - 1);

    for (int i = threadIdx.x; i < NB2MAX; i += P1_TH) hist[i] = 0;
    __syncthreads();

    int myc[P1_EPT];
    #pragma unroll
    for (int k = 0; k < P1_EPT; ++k) {
        int idx = base + (k << 9) + threadIdx.x;
        int c = (idx < E) ? col[idx] : -1;
        myc[k] = c;
        if (c >= 0) atomicAdd(&hist[c >> BSH2], 1);
    }
    __syncthreads();

    scan1024(hist, lstart, wsum);

    for (int b = threadIdx.x; b < nb2; b += P1_TH) {
        int c = hist[b];
        int off = 0;
        if (c > 0) off = atomicAdd(&gcount[(s * NB2MAX + b) * GSPREAD], c);
        gbase[b] = b * CAP + s * SUBCAP + off - lstart[b];
    }
    __syncthreads();
    for (int b = threadIdx.x; b < NB2MAX; b += P1_TH) hist[b] = lstart[b];
    __syncthreads();

    #pragma unroll
    for (int k = 0; k < P1_EPT; ++k) {
        int idx = base + (k << 9) + threadIdx.x;
        if (idx < E) {
            int c = myc[k];
            int b = c >> BSH2;
            int r = row[idx];
            int pos = atomicAdd(&hist[b], 1);
            srec[pos] = (r << BSH2) | (c & (BW2 - 1));
            sbuck[pos] = (unsigned short)b;
        }
    }
    __syncthreads();

    // dense write-out; static trip count for full batches (8 stores in flight)
    if (nE == P1_BATCH) {
        #pragma unroll
        for (int k = 0; k < P1_BATCH / P1_TH; ++k) {
            int i = (k << 9) + threadIdx.x;
            tmp[gbase[sbuck[i]] + i] = srec[i];
        }
    } else {
        for (int i = threadIdx.x; i < nE; i += P1_TH)
            tmp[gbase[sbuck[i]] + i] = srec[i];
    }
}

// ---- pass 2: one block per 256-node bucket. Stage the 8 sub-runs into LDS
//      (single global read of tmp) while building the dst histogram, then
//      scan + scatter from LDS into the ZERO-PADDED eg (x32 lists, sentinel
//      row N, byte offsets <<7). Fused s0 init (s0 = fp16(dis*x)) and the
//      sentinel zero rows for both fp16 tables (block 0). ----
__global__ __launch_bounds__(512) void bin_kernel(
        const int* __restrict__ tmp, const int* __restrict__ gcount,
        int* __restrict__ eg, int2* __restrict__ sd, float* __restrict__ dis,
        const float4* __restrict__ uev, const float4* __restrict__ mev,
        uint2* __restrict__ s0v, uint2* __restrict__ sbz,
        int n_users, int N) {
    __shared__ int srec[CAP];        // 40 KB staged records
    __shared__ int hist[BW2];
    __shared__ int padh[BW2];
    __shared__ int lstart[BW2];
    __shared__ int wsum[4];
    __shared__ float sdis[BW2];
    int b = blockIdx.x;
    int rbase = b * CAP;             // tmp region
    int ebase = b * EGCAP;           // eg region (padded)
    int c0 = b << BSH2;
    int nc = min(BW2, N - c0);
    int sent = N << 7;               // sentinel: byte offset of zero row

    for (int i = threadIdx.x; i < BW2; i += BINTH) hist[i] = 0;
    __syncthreads();

    // stage all 8 sub-runs to LDS + dst histogram (sub-loops independent -> MLP)
    int cnt = 0;
    #pragma unroll
    for (int ss = 0; ss < SUBC; ++ss) {
        int cs = gcount[(ss * NB2MAX + b) * GSPREAD];
        int sb = rbase + ss * SUBCAP;
        for (int i = threadIdx.x; i < cs; i += BINTH) {
            int rec = tmp[sb + i];
            srec[cnt + i] = rec;
            atomicAdd(&hist[rec & (BW2 - 1)], 1);
        }
        cnt += cs;
    }
    __syncthreads();

    // padded counts (multiple of 32)
    for (int c = threadIdx.x; c < BW2; c += BINTH)
        padh[c] = (hist[c] + 31) & ~31;
    __syncthreads();

    scan256(padh, lstart, wsum);     // prefix over padded counts

    // per-node metadata: sd = (padded start, padded count), dis = rsqrt(true deg)
    for (int c = threadIdx.x; c < nc; c += BINTH) {
        int d = hist[c];
        float dn = (d > 0) ? rsqrtf((float)d) : 0.0f;
        sd[c0 + c] = make_int2(ebase + lstart[c], padh[c]);
        dis[c0 + c] = dn;
        sdis[c] = dn;
    }
    __syncthreads();
    for (int i = threadIdx.x; i < BW2; i += BINTH) hist[i] = lstart[i];  // cursors
    __syncthreads();

    // scatter src byte-offsets (src*128) from LDS
    for (int i = threadIdx.x; i < cnt; i += BINTH) {
        int v = srec[i];
        int pos = atomicAdd(&hist[v & (BW2 - 1)], 1);
        eg[ebase + pos] = (v >> BSH2) << 7;
    }
    __syncthreads();

    // pad-fill: cursor = lstart+deg; fill up to lstart+padh (<32/node) with sentinel
    for (int i = threadIdx.x; i < BW2 * 32; i += BINTH) {
        int c = i >> 5;
        int o = i & 31;
        int st = hist[c];
        int en = lstart[c] + padh[c];
        if (st + o < en) eg[ebase + st + o] = sent;
    }
    // 64 slack slots after the last list (covers the gather's 2-deep prefetch)
    int tot = lstart[BW2 - 1] + padh[BW2 - 1];
    if (threadIdx.x < 64) eg[ebase + tot + threadIdx.x] = sent;

    // sentinel zero rows for both fp16 tables (replaces two memsets)
    if (b == 0 && threadIdx.x < 32) {
        int q = threadIdx.x & 15;
        uint2 z = make_uint2(0u, 0u);
        if (threadIdx.x < 16) s0v[(long long)N * 16 + q] = z;
        else                  sbz[(long long)N * 16 + q] = z;
    }

    // fused s0 init for this bucket's nodes: s0 = fp16(dis*x)
    for (int i = threadIdx.x; i < nc * 16; i += BINTH) {
        int loc = i >> 4;
        int node = c0 + loc;
        int q = i & 15;
        const float4* src = (node < n_users) ? (uev + (long long)node * 16)
                                             : (mev + (long long)(node - n_users) * 16);
        float4 v = src[q];
        float dn = sdis[loc];
        pk_u w0, w1;
        w0.h[0] = (half_t)(v.x * dn); w0.h[1] = (half_t)(v.y * dn);
        w1.h[0] = (half_t)(v.z * dn); w1.h[1] = (half_t)(v.w * dn);
        s0v[(long long)node * 16 + q] = make_uint2(w0.u, w1.u);
    }
}

// ---------------- pull propagate: 8 lanes/row (dwordx4), 8 edge phases --------
// (round-4/6/9 proven structure: 94 us/layer = bytes/3.85 TB/s wall — UNCHANGED)
// lane l: p=l&7 owns dims 8p..8p+7 (one uint4/row); h=l>>3 owns edge (j+8k+h).
// Lists zero-padded to x32 (sentinel row N = zeros): branch-free, predicate-free.
// 2-deep eg prefetch (safe via 64 sentinel slack slots per bucket).
// LAYER 1: reads s0, writes s1 + u1=fp16(a1) (u1 stride-16 rows, aliases tmp)
// LAYER 2: reads s1, writes s2 + u2=fp16(a2) (u2 stride-32 rows, lives in out)
// LAYER 3: reads s2 + x + u1 + u2, writes out = (x+u1+u2+a3)/4
template <int LAYER>
__global__ __launch_bounds__(256) void gather_kernel(
        const int* __restrict__ eg, const int2* __restrict__ sd,
        const float* __restrict__ dis,
        const uint4* __restrict__ tab, uint2* __restrict__ sOut,
        uint2* __restrict__ uOut,
        const uint2* __restrict__ u1, const uint2* __restrict__ u2,
        const float4* __restrict__ uev, const float4* __restrict__ mev,
        float4* __restrict__ outv, int n_users, int N) {
    int wave = blockIdx.x * (blockDim.x >> 6) + (threadIdx.x >> 6);
    if (wave >= N) return;
    int l = threadIdx.x & 63;
    int p = l & 7;
    int h = l >> 3;
    unsigned pb = (unsigned)p << 4;          // byte offset of this lane's uint4
    const char* tb = (const char*)tab;

    int2 se = sd[wave];
    int j = se.x;
    int e = se.x + se.y;                     // se.y = padded count (x32)
    pk_u a0, a1, a2, a3;
    a0.u = 0; a1.u = 0; a2.u = 0; a3.u = 0;

    if (j < e) {
        int r0 = eg[j + h];
        int r1 = eg[j + 8 + h];
        int r2 = eg[j + 16 + h];
        int r3 = eg[j + 24 + h];
        for (; j < e; j += 32) {
            int n0 = eg[j + 32 + h];         // prefetch next chunk (slack-safe)
            int n1 = eg[j + 40 + h];
            int n2 = eg[j + 48 + h];
            int n3 = eg[j + 56 + h];
            // eg stores src*128 (byte offset); + pb = this lane's uint4
            uint4 v0 = *(const uint4*)(tb + ((unsigned)r0 + pb));
            uint4 v1 = *(const uint4*)(tb + ((unsigned)r1 + pb));
            uint4 v2 = *(const uint4*)(tb + ((unsigned)r2 + pb));
            uint4 v3 = *(const uint4*)(tb + ((unsigned)r3 + pb));
            pk_u t;
            t.u = v0.x; a0.h += t.h; t.u = v0.y; a1.h += t.h;
            t.u = v0.z; a2.h += t.h; t.u = v0.w; a3.h += t.h;
            t.u = v1.x; a0.h += t.h; t.u = v1.y; a1.h += t.h;
            t.u = v1.z; a2.h += t.h; t.u = v1.w; a3.h += t.h;
            t.u = v2.x; a0.h += t.h; t.u = v2.y; a1.h += t.h;
            t.u = v2.z; a2.h += t.h; t.u = v2.w; a3.h += t.h;
            t.u = v3.x; a0.h += t.h; t.u = v3.y; a1.h += t.h;
            t.u = v3.z; a2.h += t.h; t.u = v3.w; a3.h += t.h;
            r0 = n0; r1 = n1; r2 = n2; r3 = n3;
        }
    }

    // reduce across the 8 edge-phases (packed); all lanes end with full sums
    #pragma unroll
    for (int m = 8; m <= 32; m <<= 1) {
        pk_u t;
        t.u = (unsigned int)__shfl_xor((int)a0.u, m); a0.h += t.h;
        t.u = (unsigned int)__shfl_xor((int)a1.u, m); a1.h += t.h;
        t.u = (unsigned int)__shfl_xor((int)a2.u, m); a2.h += t.h;
        t.u = (unsigned int)__shfl_xor((int)a3.u, m); a3.h += t.h;
    }

    if (h < 2) {                             // 16 lanes handle the 64-dim row
        pk_u x0 = h ? a2 : a0;
        pk_u x1 = h ? a3 : a1;
        float dc = dis[wave];
        float g0 = dc * (float)x0.h[0];
        float g1 = dc * (float)x0.h[1];
        float g2 = dc * (float)x1.h[0];
        float g3 = dc * (float)x1.h[1];
        int q = p * 2 + h;
        long long o16 = (long long)wave * 16 + q;
        if (LAYER < 3) {
            pk_u w0, w1, uw0, uw1;
            w0.h[0] = (half_t)(dc * g0); w0.h[1] = (half_t)(dc * g1);
            w1.h[0] = (half_t)(dc * g2); w1.h[1] = (half_t)(dc * g3);
            uw0.h[0] = (half_t)g0; uw0.h[1] = (half_t)g1;
            uw1.h[0] = (half_t)g2; uw1.h[1] = (half_t)g3;
            sOut[o16] = make_uint2(w0.u, w1.u);
            long long uo = (LAYER == 1) ? o16 : ((long long)wave * 32 + q);
            uOut[uo] = make_uint2(uw0.u, uw1.u);
        } else {
            const float4* src = (wave < n_users) ? (uev + (long long)wave * 16)
                                                 : (mev + (long long)(wave - n_users) * 16);
            float4 xv = src[q];
            uint2 ua2 = u1[o16];
            uint2 ub2 = u2[(long long)wave * 32 + q];
            pk_u pa, pb2, pc, pd;
            pa.u = ua2.x; pb2.u = ua2.y; pc.u = ub2.x; pd.u = ub2.y;
            float4 r;
            r.x = (xv.x + (float)pa.h[0]  + (float)pc.h[0] + g0) * 0.25f;
            r.y = (xv.y + (float)pa.h[1]  + (float)pc.h[1] + g1) * 0.25f;
            r.z = (xv.z + (float)pb2.h[0] + (float)pd.h[0] + g2) * 0.25f;
            r.w = (xv.w + (float)pb2.h[1] + (float)pd.h[1] + g3) * 0.25f;
            outv[o16] = r;                   // same-row in-place over u2: load-before-store
        }
    }
}

extern "C" void kernel_launch(void* const* d_in, const int* in_sizes, int n_in,
                              void* d_out, int out_size, void* d_ws, size_t ws_size,
                              hipStream_t stream) {
    const int*   edge = (const int*)d_in[0];    // [2, E]: row then col
    const float* ue   = (const float*)d_in[2];
    const float* me   = (const float*)d_in[3];
    float*       out  = (float*)d_out;

    const int E        = in_sizes[0] / 2;
    const int n_users  = in_sizes[2] / EMB;
    const int n_movies = in_sizes[3] / EMB;
    const int N        = n_users + n_movies;
    const int* row = edge;
    const int* col = edge + E;
    const int nb2 = (N + BW2 - 1) >> BSH2;      // 586 coarse buckets

    // workspace layout
    char* ws = (char*)d_ws;
    auto align_up = [](size_t v) { return (v + 255) & ~(size_t)255; };
    int*    gcount = (int*)ws;    ws += align_up((size_t)NB2MAX * SUBC * GSPREAD * sizeof(int));
    int2*   sd     = (int2*)ws;   ws += align_up((size_t)N * sizeof(int2));
    float*  dis    = (float*)ws;  ws += align_up((size_t)N * sizeof(float));
    int*    tmp    = (int*)ws;    ws += align_up((size_t)nb2 * CAP * sizeof(int));
    int*    eg     = (int*)ws;    ws += align_up((size_t)nb2 * EGCAP * sizeof(int));
    half_t* sA     = (half_t*)ws; ws += align_up((size_t)(N + 1) * EMB * sizeof(half_t));
    half_t* sB     = (half_t*)ws; ws += align_up((size_t)(N + 1) * EMB * sizeof(half_t));
    // u1 = fp16(a1), stride-16 rows: aliases tmp (dead after bin_kernel; 19.2<=24MB)
    uint2* u1 = (uint2*)tmp;
    // u2 = fp16(a2), stride-32 rows: lives in the (unwritten) out buffer
    uint2* u2 = (uint2*)out;

    // two-pass counting sort -> padded CSR (deg/dis/s0/zero-rows fused in pass 2)
    hipMemsetAsync(gcount, 0, (size_t)NB2MAX * SUBC * GSPREAD * sizeof(int), stream);
    part_kernel<<<(E + P1_BATCH - 1) / P1_BATCH, P1_TH, 0, stream>>>(
        row, col, gcount, tmp, E, nb2);
    bin_kernel<<<nb2, BINTH, 0, stream>>>(
        tmp, gcount, eg, sd, dis,
        (const float4*)ue, (const float4*)me, (uint2*)sA, (uint2*)sB,
        n_users, N);

    // 3 propagation layers (atomic-free pull, packed fp16, no out RMW)
    const int waves_per_block = 4;   // 256 threads
    const int gblocks = (N + waves_per_block - 1) / waves_per_block;
    gather_kernel<1><<<gblocks, 256, 0, stream>>>(
        eg, sd, dis, (const uint4*)sA, (uint2*)sB, u1,
        nullptr, nullptr, nullptr, nullptr, nullptr, n_users, N);
    gather_kernel<2><<<gblocks, 256, 0, stream>>>(
        eg, sd, dis, (const uint4*)sB, (uint2*)sA, u2,
        nullptr, nullptr, nullptr, nullptr, nullptr, n_users, N);
    gather_kernel<3><<<gblocks, 256, 0, stream>>>(
        eg, sd, dis, (const uint4*)sA, nullptr, nullptr,
        (const uint2*)u1, (const uint2*)u2,
        (const float4*)ue, (const float4*)me, (float4*)out, n_users, N);
}

// Round 11
// 444.215 us; speedup vs baseline: 1.3960x; 1.0406x over previous
//
#include <hip/hip_runtime.h>

typedef _Float16 half_t;
typedef _Float16 half2_t __attribute__((ext_vector_type(2)));
union pk_u { unsigned int u; half2_t h; };

#define EMB 64
#define NLAYERS 3
#define BSH2 8
#define BW2 256            // nodes per coarse bucket
#define NB2MAX 1024        // max bucket count (N<=262144)
#define GSPREAD 32         // counter stride: one counter per 128-B line
#define SUBC 8             // sub-counters per bucket (one per XCD class)
#define CAP 10240          // tmp region per bucket = SUBC * SUBCAP
#define SUBCAP 1280        // per (bucket, xcd-class) sub-region (mean 1066, +6.5 sigma)
#define EGCAP 16384        // eg region per bucket: 32-padded lists (avg ~12.6K) + slack
#define P1_BATCH 8192      // doubled: write runs 7 -> 14 records (coalescing)
#define P1_TH 1024         // keeps 32 waves/CU at 2 blocks/CU (LDS 61.5 KB)
#define P1_EPT 8           // edges per thread in part_kernel (8192/1024)
#define BINTH 512

// ---- register-only inclusive scan within a 64-lane wave ----
__device__ inline int wave_incl_scan(int v) {
    #pragma unroll
    for (int off = 1; off < 64; off <<= 1) {
        int u = __shfl_up(v, off);
        if ((threadIdx.x & 63) >= off) v += u;
    }
    return v;
}

// ---- 1024-entry exclusive scan, 1024 threads (1 entry each), 2 barriers ----
__device__ inline void scan1024(const int* __restrict__ in, int* __restrict__ lstart,
                                int* __restrict__ wsum) {
    int t = threadIdx.x;
    int orig = in[t];
    int v = wave_incl_scan(orig);
    if ((t & 63) == 63) wsum[t >> 6] = v;
    __syncthreads();
    int wid = t >> 6;
    int base = 0;
    #pragma unroll
    for (int w = 0; w < 15; ++w) base += (w < wid) ? wsum[w] : 0;
    lstart[t] = base + v - orig;
    __syncthreads();
}

// ---- 256-entry exclusive scan, first 256 of 512 threads, 2 barriers ----
__device__ inline void scan256(const int* __restrict__ in, int* __restrict__ lstart,
                               int* __restrict__ wsum) {
    int t = threadIdx.x;
    int v = 0, orig = 0;
    if (t < 256) {                       // waves 0-3 fully active: shfl is safe
        orig = in[t];
        v = wave_incl_scan(orig);
        if ((t & 63) == 63) wsum[t >> 6] = v;
    }
    __syncthreads();
    if (t < 256) {
        int wid = t >> 6;
        int base = 0;
        #pragma unroll
        for (int w = 0; w < 3; ++w) base += (w < wid) ? wsum[w] : 0;
        lstart[t] = base + v - orig;
    }
    __syncthreads();
}

// ---- pass 1: partition edges into 256-node buckets, LDS-sorted dense writes ----
// record = (row<<8)|(col&255)
// gcount[(s*NB2MAX+b)*GSPREAD], s = blockIdx&7: XCD-local counter lines.
__global__ __launch_bounds__(1024) void part_kernel(
        const int* __restrict__ row, const int* __restrict__ col,
        int* __restrict__ gcount, int* __restrict__ tmp, int E, int nb2) {
    __shared__ int hist[NB2MAX];
    __shared__ int lstart[NB2MAX];
    __shared__ int gbase[NB2MAX];
    __shared__ int wsum[16];
    __shared__ int srec[P1_BATCH];
    __shared__ unsigned short sbuck[P1_BATCH];

    int base = blockIdx.x * P1_BATCH;
    int nE = min(P1_BATCH, E - base);
    int s = blockIdx.x & (SUBC - 1);

    if (threadIdx.x < NB2MAX) hist[threadIdx.x] = 0;
    __syncthreads();

    int myc[P1_EPT];
    #pragma unroll
    for (int k = 0; k < P1_EPT; ++k) {
        int idx = base + (k << 10) + threadIdx.x;
        int c = (idx < E) ? col[idx] : -1;
        myc[k] = c;
        if (c >= 0) atomicAdd(&hist[c >> BSH2], 1);
    }
    __syncthreads();

    scan1024(hist, lstart, wsum);

    if (threadIdx.x < nb2) {
        int b = threadIdx.x;
        int c = hist[b];
        int off = 0;
        if (c > 0) off = atomicAdd(&gcount[(s * NB2MAX + b) * GSPREAD], c);
        gbase[b] = b * CAP + s * SUBCAP + off - lstart[b];
    }
    __syncthreads();
    if (threadIdx.x < NB2MAX) hist[threadIdx.x] = lstart[threadIdx.x];
    __syncthreads();

    #pragma unroll
    for (int k = 0; k < P1_EPT; ++k) {
        int idx = base + (k << 10) + threadIdx.x;
        if (idx < E) {
            int c = myc[k];
            int b = c >> BSH2;
            int r = row[idx];
            int pos = atomicAdd(&hist[b], 1);
            srec[pos] = (r << BSH2) | (c & (BW2 - 1));
            sbuck[pos] = (unsigned short)b;
        }
    }
    __syncthreads();

    // dense write-out; static trip count for full batches (8 stores in flight)
    if (nE == P1_BATCH) {
        #pragma unroll
        for (int k = 0; k < P1_BATCH / P1_TH; ++k) {
            int i = (k << 10) + threadIdx.x;
            tmp[gbase[sbuck[i]] + i] = srec[i];
        }
    } else {
        for (int i = threadIdx.x; i < nE; i += P1_TH)
            tmp[gbase[sbuck[i]] + i] = srec[i];
    }
}

// ---- pass 2: one block per 256-node bucket. Stage the 8 sub-runs into LDS
//      (single global read of tmp) while building the dst histogram, then
//      scan + scatter from LDS into the ZERO-PADDED eg (x32 lists, sentinel
//      row N, byte offsets <<7). Fused s0 init (s0 = fp16(dis*x)) and the
//      sentinel zero rows for both fp16 tables (block 0). ----
__global__ __launch_bounds__(512) void bin_kernel(
        const int* __restrict__ tmp, const int* __restrict__ gcount,
        int* __restrict__ eg, int2* __restrict__ sd, float* __restrict__ dis,
        const float4* __restrict__ uev, const float4* __restrict__ mev,
        uint2* __restrict__ s0v, uint2* __restrict__ sbz,
        int n_users, int N) {
    __shared__ int srec[CAP];        // 40 KB staged records
    __shared__ int hist[BW2];
    __shared__ int padh[BW2];
    __shared__ int lstart[BW2];
    __shared__ int wsum[4];
    __shared__ float sdis[BW2];
    int b = blockIdx.x;
    int rbase = b * CAP;             // tmp region
    int ebase = b * EGCAP;           // eg region (padded)
    int c0 = b << BSH2;
    int nc = min(BW2, N - c0);
    int sent = N << 7;               // sentinel: byte offset of zero row

    for (int i = threadIdx.x; i < BW2; i += BINTH) hist[i] = 0;
    __syncthreads();

    // stage all 8 sub-runs to LDS + dst histogram (sub-loops independent -> MLP)
    int cnt = 0;
    #pragma unroll
    for (int ss = 0; ss < SUBC; ++ss) {
        int cs = gcount[(ss * NB2MAX + b) * GSPREAD];
        int sb = rbase + ss * SUBCAP;
        for (int i = threadIdx.x; i < cs; i += BINTH) {
            int rec = tmp[sb + i];
            srec[cnt + i] = rec;
            atomicAdd(&hist[rec & (BW2 - 1)], 1);
        }
        cnt += cs;
    }
    __syncthreads();

    // padded counts (multiple of 32)
    for (int c = threadIdx.x; c < BW2; c += BINTH)
        padh[c] = (hist[c] + 31) & ~31;
    __syncthreads();

    scan256(padh, lstart, wsum);     // prefix over padded counts

    // per-node metadata: sd = (padded start, padded count), dis = rsqrt(true deg)
    for (int c = threadIdx.x; c < nc; c += BINTH) {
        int d = hist[c];
        float dn = (d > 0) ? rsqrtf((float)d) : 0.0f;
        sd[c0 + c] = make_int2(ebase + lstart[c], padh[c]);
        dis[c0 + c] = dn;
        sdis[c] = dn;
    }
    __syncthreads();
    for (int i = threadIdx.x; i < BW2; i += BINTH) hist[i] = lstart[i];  // cursors
    __syncthreads();

    // scatter src byte-offsets (src*128) from LDS
    for (int i = threadIdx.x; i < cnt; i += BINTH) {
        int v = srec[i];
        int pos = atomicAdd(&hist[v & (BW2 - 1)], 1);
        eg[ebase + pos] = (v >> BSH2) << 7;
    }
    __syncthreads();

    // pad-fill: cursor = lstart+deg; fill up to lstart+padh (<32/node) with sentinel
    for (int i = threadIdx.x; i < BW2 * 32; i += BINTH) {
        int c = i >> 5;
        int o = i & 31;
        int st = hist[c];
        int en = lstart[c] + padh[c];
        if (st + o < en) eg[ebase + st + o] = sent;
    }
    // 64 slack slots after the last list (covers the gather's 2-deep prefetch)
    int tot = lstart[BW2 - 1] + padh[BW2 - 1];
    if (threadIdx.x < 64) eg[ebase + tot + threadIdx.x] = sent;

    // sentinel zero rows for both fp16 tables (replaces two memsets)
    if (b == 0 && threadIdx.x < 32) {
        int q = threadIdx.x & 15;
        uint2 z = make_uint2(0u, 0u);
        if (threadIdx.x < 16) s0v[(long long)N * 16 + q] = z;
        else                  sbz[(long long)N * 16 + q] = z;
    }

    // fused s0 init for this bucket's nodes: s0 = fp16(dis*x)
    for (int i = threadIdx.x; i < nc * 16; i += BINTH) {
        int loc = i >> 4;
        int node = c0 + loc;
        int q = i & 15;
        const float4* src = (node < n_users) ? (uev + (long long)node * 16)
                                             : (mev + (long long)(node - n_users) * 16);
        float4 v = src[q];
        float dn = sdis[loc];
        pk_u w0, w1;
        w0.h[0] = (half_t)(v.x * dn); w0.h[1] = (half_t)(v.y * dn);
        w1.h[0] = (half_t)(v.z * dn); w1.h[1] = (half_t)(v.w * dn);
        s0v[(long long)node * 16 + q] = make_uint2(w0.u, w1.u);
    }
}

// ---------------- pull propagate: 8 lanes/row (dwordx4), 8 edge phases --------
// NO u-tables: a_k = s_k/dc exactly (same single fp16 rounding as storing
// fp16(a_k)); layers 1-2 write ONLY s_k (WRITE halved 37.5->18.75 MB).
// LAYER 3 reads s1[node], s2[node] + x, out = (x + s1/dc + s2/dc + a3)/4.
// lane l: p=l&7 owns dims 8p..8p+7 (one uint4/row); h=l>>3 owns edge (j+8k+h).
// Lists zero-padded to x32 (sentinel row N = zeros): branch-free, predicate-free.
// 2-deep eg prefetch (safe via 64 sentinel slack slots per bucket).
template <int LAYER>
__global__ __launch_bounds__(256) void gather_kernel(
        const int* __restrict__ eg, const int2* __restrict__ sd,
        const float* __restrict__ dis,
        const uint4* __restrict__ tab, uint2* __restrict__ sOut,
        const uint2* __restrict__ s1v, const uint2* __restrict__ s2v,
        const float4* __restrict__ uev, const float4* __restrict__ mev,
        float4* __restrict__ outv, int n_users, int N) {
    int wave = blockIdx.x * (blockDim.x >> 6) + (threadIdx.x >> 6);
    if (wave >= N) return;
    int l = threadIdx.x & 63;
    int p = l & 7;
    int h = l >> 3;
    unsigned pb = (unsigned)p << 4;          // byte offset of this lane's uint4
    const char* tb = (const char*)tab;

    int2 se = sd[wave];
    int j = se.x;
    int e = se.x + se.y;                     // se.y = padded count (x32)
    pk_u a0, a1, a2, a3;
    a0.u = 0; a1.u = 0; a2.u = 0; a3.u = 0;

    if (j < e) {
        int r0 = eg[j + h];
        int r1 = eg[j + 8 + h];
        int r2 = eg[j + 16 + h];
        int r3 = eg[j + 24 + h];
        for (; j < e; j += 32) {
            int n0 = eg[j + 32 + h];         // prefetch next chunk (slack-safe)
            int n1 = eg[j + 40 + h];
            int n2 = eg[j + 48 + h];
            int n3 = eg[j + 56 + h];
            // eg stores src*128 (byte offset); + pb = this lane's uint4
            uint4 v0 = *(const uint4*)(tb + ((unsigned)r0 + pb));
            uint4 v1 = *(const uint4*)(tb + ((unsigned)r1 + pb));
            uint4 v2 = *(const uint4*)(tb + ((unsigned)r2 + pb));
            uint4 v3 = *(const uint4*)(tb + ((unsigned)r3 + pb));
            pk_u t;
            t.u = v0.x; a0.h += t.h; t.u = v0.y; a1.h += t.h;
            t.u = v0.z; a2.h += t.h; t.u = v0.w; a3.h += t.h;
            t.u = v1.x; a0.h += t.h; t.u = v1.y; a1.h += t.h;
            t.u = v1.z; a2.h += t.h; t.u = v1.w; a3.h += t.h;
            t.u = v2.x; a0.h += t.h; t.u = v2.y; a1.h += t.h;
            t.u = v2.z; a2.h += t.h; t.u = v2.w; a3.h += t.h;
            t.u = v3.x; a0.h += t.h; t.u = v3.y; a1.h += t.h;
            t.u = v3.z; a2.h += t.h; t.u = v3.w; a3.h += t.h;
            r0 = n0; r1 = n1; r2 = n2; r3 = n3;
        }
    }

    // reduce across the 8 edge-phases (packed); all lanes end with full sums
    #pragma unroll
    for (int m = 8; m <= 32; m <<= 1) {
        pk_u t;
        t.u = (unsigned int)__shfl_xor((int)a0.u, m); a0.h += t.h;
        t.u = (unsigned int)__shfl_xor((int)a1.u, m); a1.h += t.h;
        t.u = (unsigned int)__shfl_xor((int)a2.u, m); a2.h += t.h;
        t.u = (unsigned int)__shfl_xor((int)a3.u, m); a3.h += t.h;
    }

    if (h < 2) {                             // 16 lanes handle the 64-dim row
        pk_u x0 = h ? a2 : a0;
        pk_u x1 = h ? a3 : a1;
        float dc = dis[wave];
        float g0 = dc * (float)x0.h[0];
        float g1 = dc * (float)x0.h[1];
        float g2 = dc * (float)x1.h[0];
        float g3 = dc * (float)x1.h[1];
        int q = p * 2 + h;
        long long o16 = (long long)wave * 16 + q;
        if (LAYER < 3) {
            pk_u w0, w1;
            w0.h[0] = (half_t)(dc * g0); w0.h[1] = (half_t)(dc * g1);
            w1.h[0] = (half_t)(dc * g2); w1.h[1] = (half_t)(dc * g3);
            sOut[o16] = make_uint2(w0.u, w1.u);
        } else {
            const float4* src = (wave < n_users) ? (uev + (long long)wave * 16)
                                                 : (mev + (long long)(wave - n_users) * 16);
            float4 xv = src[q];
            float inv = (dc > 0.0f) ? (1.0f / dc) : 0.0f;
            uint2 sa2 = s1v[o16];            // s1[node] = fp16(dc*a1)
            uint2 sb2 = s2v[o16];            // s2[node] = fp16(dc*a2)
            pk_u pa, pb2, pc, pd;
            pa.u = sa2.x; pb2.u = sa2.y; pc.u = sb2.x; pd.u = sb2.y;
            float4 r;
            r.x = (xv.x + ((float)pa.h[0]  + (float)pc.h[0]) * inv + g0) * 0.25f;
            r.y = (xv.y + ((float)pa.h[1]  + (float)pc.h[1]) * inv + g1) * 0.25f;
            r.z = (xv.z + ((float)pb2.h[0] + (float)pd.h[0]) * inv + g2) * 0.25f;
            r.w = (xv.w + ((float)pb2.h[1] + (float)pd.h[1]) * inv + g3) * 0.25f;
            outv[o16] = r;
        }
    }
}

extern "C" void kernel_launch(void* const* d_in, const int* in_sizes, int n_in,
                              void* d_out, int out_size, void* d_ws, size_t ws_size,
                              hipStream_t stream) {
    const int*   edge = (const int*)d_in[0];    // [2, E]: row then col
    const float* ue   = (const float*)d_in[2];
    const float* me   = (const float*)d_in[3];
    float*       out  = (float*)d_out;

    const int E        = in_sizes[0] / 2;
    const int n_users  = in_sizes[2] / EMB;
    const int n_movies = in_sizes[3] / EMB;
    const int N        = n_users + n_movies;
    const int* row = edge;
    const int* col = edge + E;
    const int nb2 = (N + BW2 - 1) >> BSH2;      // 586 coarse buckets

    // workspace layout
    char* ws = (char*)d_ws;
    auto align_up = [](size_t v) { return (v + 255) & ~(size_t)255; };
    int*    gcount = (int*)ws;    ws += align_up((size_t)NB2MAX * SUBC * GSPREAD * sizeof(int));
    int2*   sd     = (int2*)ws;   ws += align_up((size_t)N * sizeof(int2));
    float*  dis    = (float*)ws;  ws += align_up((size_t)N * sizeof(float));
    int*    tmp    = (int*)ws;    ws += align_up((size_t)nb2 * CAP * sizeof(int));
    int*    eg     = (int*)ws;    ws += align_up((size_t)nb2 * EGCAP * sizeof(int));
    half_t* sA     = (half_t*)ws; ws += align_up((size_t)(N + 1) * EMB * sizeof(half_t));
    half_t* sB     = (half_t*)ws; ws += align_up((size_t)(N + 1) * EMB * sizeof(half_t));

    // two-pass counting sort -> padded CSR (deg/dis/s0/zero-rows fused in pass 2)
    hipMemsetAsync(gcount, 0, (size_t)NB2MAX * SUBC * GSPREAD * sizeof(int), stream);
    part_kernel<<<(E + P1_BATCH - 1) / P1_BATCH, P1_TH, 0, stream>>>(
        row, col, gcount, tmp, E, nb2);
    bin_kernel<<<nb2, BINTH, 0, stream>>>(
        tmp, gcount, eg, sd, dis,
        (const float4*)ue, (const float4*)me, (uint2*)sA, (uint2*)sB,
        n_users, N);

    // 3 propagation layers (atomic-free pull, packed fp16; s-tables only:
    // g1 writes s1->sB, g2 writes s2->sA, g3 reads s2-table(sA) + s1/s2 per-node)
    const int waves_per_block = 4;   // 256 threads
    const int gblocks = (N + waves_per_block - 1) / waves_per_block;
    gather_kernel<1><<<gblocks, 256, 0, stream>>>(
        eg, sd, dis, (const uint4*)sA, (uint2*)sB,
        nullptr, nullptr, nullptr, nullptr, nullptr, n_users, N);
    gather_kernel<2><<<gblocks, 256, 0, stream>>>(
        eg, sd, dis, (const uint4*)sB, (uint2*)sA,
        nullptr, nullptr, nullptr, nullptr, nullptr, n_users, N);
    gather_kernel<3><<<gblocks, 256, 0, stream>>>(
        eg, sd, dis, (const uint4*)sA, nullptr,
        (const uint2*)sB, (const uint2*)sA,
        (const float4*)ue, (const float4*)me, (float4*)out, n_users, N);
}

// Round 12
// 443.399 us; speedup vs baseline: 1.3986x; 1.0018x over previous
//
#include <hip/hip_runtime.h>

typedef _Float16 half_t;
typedef _Float16 half2_t __attribute__((ext_vector_type(2)));
union pk_u { unsigned int u; half2_t h; };

#define EMB 64
#define NLAYERS 3
#define BSH2 8
#define BW2 256            // nodes per coarse bucket (part granularity)
#define HB 128             // nodes per bin half-bucket
#define NB2MAX 1024        // max bucket count (N<=262144)
#define GSPREAD 32         // counter stride: one counter per 128-B line
#define SUBC 8             // sub-counters per bucket (one per XCD class)
#define CAP 10240          // tmp region per bucket = SUBC * SUBCAP
#define SUBCAP 1280        // per (bucket, xcd-class) sub-region (mean 1066, +6.5 sigma)
#define SRECMAX 5376       // bin: staged records per half-bucket (mean 4266, huge margin)
#define EGIMG 9408         // bin: LDS eg image (SRECMAX + 128*31 pad + 64 slack)
#define EGCAP EGIMG        // eg region per half-bucket
#define P1_BATCH 8192
#define P1_TH 1024
#define P1_EPT 8           // edges per thread in part_kernel (8192/1024)
#define BINTH 512

// ---- register-only inclusive scan within a 64-lane wave ----
__device__ inline int wave_incl_scan(int v) {
    #pragma unroll
    for (int off = 1; off < 64; off <<= 1) {
        int u = __shfl_up(v, off);
        if ((threadIdx.x & 63) >= off) v += u;
    }
    return v;
}

// ---- 1024-entry exclusive scan, 1024 threads (1 entry each), 2 barriers ----
__device__ inline void scan1024(const int* __restrict__ in, int* __restrict__ lstart,
                                int* __restrict__ wsum) {
    int t = threadIdx.x;
    int orig = in[t];
    int v = wave_incl_scan(orig);
    if ((t & 63) == 63) wsum[t >> 6] = v;
    __syncthreads();
    int wid = t >> 6;
    int base = 0;
    #pragma unroll
    for (int w = 0; w < 15; ++w) base += (w < wid) ? wsum[w] : 0;
    lstart[t] = base + v - orig;
    __syncthreads();
}

// ---- 128-entry exclusive scan, first 128 of 512 threads, 2 barriers ----
__device__ inline void scan128(const int* __restrict__ in, int* __restrict__ lstart,
                               int* __restrict__ wsum) {
    int t = threadIdx.x;
    int v = 0, orig = 0;
    if (t < 128) {                       // waves 0-1 fully active: shfl is safe
        orig = in[t];
        v = wave_incl_scan(orig);
        if ((t & 63) == 63) wsum[t >> 6] = v;
    }
    __syncthreads();
    if (t < 128) {
        int base = (t >= 64) ? wsum[0] : 0;
        lstart[t] = base + v - orig;
    }
    __syncthreads();
}

// ---- pass 1: partition edges into 256-node buckets, LDS-sorted dense writes ----
// record = (row<<8)|(col&255); UNCHANGED from round 11 (proven).
__global__ __launch_bounds__(1024) void part_kernel(
        const int* __restrict__ row, const int* __restrict__ col,
        int* __restrict__ gcount, int* __restrict__ tmp, int E, int nb2) {
    __shared__ int hist[NB2MAX];
    __shared__ int lstart[NB2MAX];
    __shared__ int gbase[NB2MAX];
    __shared__ int wsum[16];
    __shared__ int srec[P1_BATCH];
    __shared__ unsigned short sbuck[P1_BATCH];

    int base = blockIdx.x * P1_BATCH;
    int nE = min(P1_BATCH, E - base);
    int s = blockIdx.x & (SUBC - 1);

    if (threadIdx.x < NB2MAX) hist[threadIdx.x] = 0;
    __syncthreads();

    int myc[P1_EPT];
    #pragma unroll
    for (int k = 0; k < P1_EPT; ++k) {
        int idx = base + (k << 10) + threadIdx.x;
        int c = (idx < E) ? col[idx] : -1;
        myc[k] = c;
        if (c >= 0) atomicAdd(&hist[c >> BSH2], 1);
    }
    __syncthreads();

    scan1024(hist, lstart, wsum);

    if (threadIdx.x < nb2) {
        int b = threadIdx.x;
        int c = hist[b];
        int off = 0;
        if (c > 0) off = atomicAdd(&gcount[(s * NB2MAX + b) * GSPREAD], c);
        gbase[b] = b * CAP + s * SUBCAP + off - lstart[b];
    }
    __syncthreads();
    if (threadIdx.x < NB2MAX) hist[threadIdx.x] = lstart[threadIdx.x];
    __syncthreads();

    #pragma unroll
    for (int k = 0; k < P1_EPT; ++k) {
        int idx = base + (k << 10) + threadIdx.x;
        if (idx < E) {
            int c = myc[k];
            int b = c >> BSH2;
            int r = row[idx];
            int pos = atomicAdd(&hist[b], 1);
            srec[pos] = (r << BSH2) | (c & (BW2 - 1));
            sbuck[pos] = (unsigned short)b;
        }
    }
    __syncthreads();

    if (nE == P1_BATCH) {
        #pragma unroll
        for (int k = 0; k < P1_BATCH / P1_TH; ++k) {
            int i = (k << 10) + threadIdx.x;
            tmp[gbase[sbuck[i]] + i] = srec[i];
        }
    } else {
        for (int i = threadIdx.x; i < nE; i += P1_TH)
            tmp[gbase[sbuck[i]] + i] = srec[i];
    }
}

// ---- pass 2: one block per 128-node HALF-bucket. Stage-filter the parent
//      bucket's 8 sub-runs by half (bit 7 of record), build the fully-sorted,
//      x32-padded, sentinel-filled eg image IN LDS, then write it to global
//      with dense int4 stores (replaces 5M scattered 4-B writes).
//      Fused: sd/dis metadata, s0 = fp16(dis*x), zero rows (block 0). ----
__global__ __launch_bounds__(512) void bin_kernel(
        const int* __restrict__ tmp, const int* __restrict__ gcount,
        int* __restrict__ eg, int2* __restrict__ sd, float* __restrict__ dis,
        const float4* __restrict__ uev, const float4* __restrict__ mev,
        uint2* __restrict__ s0v, uint2* __restrict__ sbz,
        int n_users, int N) {
    __shared__ alignas(16) int egl[EGIMG];   // sorted eg image
    __shared__ int srec[SRECMAX];            // this half's records
    __shared__ int hist[HB];
    __shared__ int padh[HB];
    __shared__ int lstart[HB];
    __shared__ int curs[HB];
    __shared__ int wsum[2];
    __shared__ float sdis[HB];
    __shared__ int nselS;

    int g = blockIdx.x;
    int b = g >> 1;                  // parent 256-bucket
    int h = g & 1;                   // half
    int rbase = b * CAP;
    int ebase = g * EGCAP;
    int c0 = (b << BSH2) + (h << 7);
    int nc = min(HB, N - c0);        // may be <=0 for tail half
    int sent = N << 7;               // sentinel: byte offset of zero row

    if (threadIdx.x < HB) hist[threadIdx.x] = 0;
    if (threadIdx.x == 0) nselS = 0;
    __syncthreads();

    // stage-filter: read parent bucket's 8 sub-runs, keep this half's records
    #pragma unroll
    for (int ss = 0; ss < SUBC; ++ss) {
        int cs = gcount[(ss * NB2MAX + b) * GSPREAD];
        int sb = rbase + ss * SUBCAP;
        for (int i = threadIdx.x; i < cs; i += BINTH) {
            int rec = tmp[sb + i];
            if (((rec >> 7) & 1) == h) {
                int pos = atomicAdd(&nselS, 1);
                if (pos < SRECMAX) srec[pos] = rec;
                atomicAdd(&hist[rec & (HB - 1)], 1);
            }
        }
    }
    __syncthreads();
    int nsel = min(nselS, SRECMAX);

    // padded counts (multiple of 32)
    if (threadIdx.x < HB) padh[threadIdx.x] = (hist[threadIdx.x] + 31) & ~31;
    __syncthreads();

    scan128(padh, lstart, wsum);

    // per-node metadata: sd = (padded start, padded count), dis = rsqrt(true deg)
    if (threadIdx.x < HB) {
        int c = threadIdx.x;
        if (c < nc) {
            int d = hist[c];
            float dn = (d > 0) ? rsqrtf((float)d) : 0.0f;
            sd[c0 + c] = make_int2(ebase + lstart[c], padh[c]);
            dis[c0 + c] = dn;
            sdis[c] = dn;
        }
        curs[c] = lstart[c];
    }
    __syncthreads();

    // scatter records into the LDS image (src byte-offset = rec>>1 & ~127)
    for (int i = threadIdx.x; i < nsel; i += BINTH) {
        int v = srec[i];
        int pos = atomicAdd(&curs[v & (HB - 1)], 1);
        egl[pos] = (v >> 1) & ~127;          // (rec>>8)<<7 = src*128
    }
    __syncthreads();

    // pad-fill inside LDS: [lstart+deg, lstart+padh) <- sentinel
    for (int i = threadIdx.x; i < HB * 32; i += BINTH) {
        int c = i >> 5;
        int o = i & 31;
        int st = lstart[c] + hist[c];
        int en = lstart[c] + padh[c];
        if (st + o < en) egl[st + o] = sent;
    }
    int tot = lstart[HB - 1] + padh[HB - 1];
    if (threadIdx.x < 64) egl[tot + threadIdx.x] = sent;   // prefetch slack
    __syncthreads();

    // dense int4 write-out of the image (tot+64 is a multiple of 4)
    int tw = (tot + 64) >> 2;
    int4* dst = (int4*)(eg + ebase);
    const int4* srci = (const int4*)egl;
    for (int i = threadIdx.x; i < tw; i += BINTH) dst[i] = srci[i];

    // sentinel zero rows for both fp16 tables (replaces two memsets)
    if (g == 0 && threadIdx.x < 32) {
        int q = threadIdx.x & 15;
        uint2 z = make_uint2(0u, 0u);
        if (threadIdx.x < 16) s0v[(long long)N * 16 + q] = z;
        else                  sbz[(long long)N * 16 + q] = z;
    }

    // fused s0 init for this half's nodes: s0 = fp16(dis*x)
    for (int i = threadIdx.x; i < nc * 16; i += BINTH) {
        int loc = i >> 4;
        int node = c0 + loc;
        int q = i & 15;
        const float4* src = (node < n_users) ? (uev + (long long)node * 16)
                                             : (mev + (long long)(node - n_users) * 16);
        float4 v = src[q];
        float dn = sdis[loc];
        pk_u w0, w1;
        w0.h[0] = (half_t)(v.x * dn); w0.h[1] = (half_t)(v.y * dn);
        w1.h[0] = (half_t)(v.z * dn); w1.h[1] = (half_t)(v.w * dn);
        s0v[(long long)node * 16 + q] = make_uint2(w0.u, w1.u);
    }
}

// ---------------- pull propagate: 8 lanes/row (dwordx4), 8 edge phases --------
// UNCHANGED from round 11 (93.4 us/layer = fetch-path wall).
// NO u-tables: a_k = s_k/dc exactly; layers 1-2 write ONLY s_k.
// LAYER 3 reads s1[node], s2[node] + x, out = (x + s1/dc + s2/dc + a3)/4.
template <int LAYER>
__global__ __launch_bounds__(256) void gather_kernel(
        const int* __restrict__ eg, const int2* __restrict__ sd,
        const float* __restrict__ dis,
        const uint4* __restrict__ tab, uint2* __restrict__ sOut,
        const uint2* __restrict__ s1v, const uint2* __restrict__ s2v,
        const float4* __restrict__ uev, const float4* __restrict__ mev,
        float4* __restrict__ outv, int n_users, int N) {
    int wave = blockIdx.x * (blockDim.x >> 6) + (threadIdx.x >> 6);
    if (wave >= N) return;
    int l = threadIdx.x & 63;
    int p = l & 7;
    int h = l >> 3;
    unsigned pb = (unsigned)p << 4;          // byte offset of this lane's uint4
    const char* tb = (const char*)tab;

    int2 se = sd[wave];
    int j = se.x;
    int e = se.x + se.y;                     // se.y = padded count (x32)
    pk_u a0, a1, a2, a3;
    a0.u = 0; a1.u = 0; a2.u = 0; a3.u = 0;

    if (j < e) {
        int r0 = eg[j + h];
        int r1 = eg[j + 8 + h];
        int r2 = eg[j + 16 + h];
        int r3 = eg[j + 24 + h];
        for (; j < e; j += 32) {
            int n0 = eg[j + 32 + h];         // prefetch next chunk (slack-safe)
            int n1 = eg[j + 40 + h];
            int n2 = eg[j + 48 + h];
            int n3 = eg[j + 56 + h];
            uint4 v0 = *(const uint4*)(tb + ((unsigned)r0 + pb));
            uint4 v1 = *(const uint4*)(tb + ((unsigned)r1 + pb));
            uint4 v2 = *(const uint4*)(tb + ((unsigned)r2 + pb));
            uint4 v3 = *(const uint4*)(tb + ((unsigned)r3 + pb));
            pk_u t;
            t.u = v0.x; a0.h += t.h; t.u = v0.y; a1.h += t.h;
            t.u = v0.z; a2.h += t.h; t.u = v0.w; a3.h += t.h;
            t.u = v1.x; a0.h += t.h; t.u = v1.y; a1.h += t.h;
            t.u = v1.z; a2.h += t.h; t.u = v1.w; a3.h += t.h;
            t.u = v2.x; a0.h += t.h; t.u = v2.y; a1.h += t.h;
            t.u = v2.z; a2.h += t.h; t.u = v2.w; a3.h += t.h;
            t.u = v3.x; a0.h += t.h; t.u = v3.y; a1.h += t.h;
            t.u = v3.z; a2.h += t.h; t.u = v3.w; a3.h += t.h;
            r0 = n0; r1 = n1; r2 = n2; r3 = n3;
        }
    }

    #pragma unroll
    for (int m = 8; m <= 32; m <<= 1) {
        pk_u t;
        t.u = (unsigned int)__shfl_xor((int)a0.u, m); a0.h += t.h;
        t.u = (unsigned int)__shfl_xor((int)a1.u, m); a1.h += t.h;
        t.u = (unsigned int)__shfl_xor((int)a2.u, m); a2.h += t.h;
        t.u = (unsigned int)__shfl_xor((int)a3.u, m); a3.h += t.h;
    }

    if (h < 2) {                             // 16 lanes handle the 64-dim row
        pk_u x0 = h ? a2 : a0;
        pk_u x1 = h ? a3 : a1;
        float dc = dis[wave];
        float g0 = dc * (float)x0.h[0];
        float g1 = dc * (float)x0.h[1];
        float g2 = dc * (float)x1.h[0];
        float g3 = dc * (float)x1.h[1];
        int q = p * 2 + h;
        long long o16 = (long long)wave * 16 + q;
        if (LAYER < 3) {
            pk_u w0, w1;
            w0.h[0] = (half_t)(dc * g0); w0.h[1] = (half_t)(dc * g1);
            w1.h[0] = (half_t)(dc * g2); w1.h[1] = (half_t)(dc * g3);
            sOut[o16] = make_uint2(w0.u, w1.u);
        } else {
            const float4* src = (wave < n_users) ? (uev + (long long)wave * 16)
                                                 : (mev + (long long)(wave - n_users) * 16);
            float4 xv = src[q];
            float inv = (dc > 0.0f) ? (1.0f / dc) : 0.0f;
            uint2 sa2 = s1v[o16];            // s1[node] = fp16(dc*a1)
            uint2 sb2 = s2v[o16];            // s2[node] = fp16(dc*a2)
            pk_u pa, pb2, pc, pd;
            pa.u = sa2.x; pb2.u = sa2.y; pc.u = sb2.x; pd.u = sb2.y;
            float4 r;
            r.x = (xv.x + ((float)pa.h[0]  + (float)pc.h[0]) * inv + g0) * 0.25f;
            r.y = (xv.y + ((float)pa.h[1]  + (float)pc.h[1]) * inv + g1) * 0.25f;
            r.z = (xv.z + ((float)pb2.h[0] + (float)pd.h[0]) * inv + g2) * 0.25f;
            r.w = (xv.w + ((float)pb2.h[1] + (float)pd.h[1]) * inv + g3) * 0.25f;
            outv[o16] = r;
        }
    }
}

extern "C" void kernel_launch(void* const* d_in, const int* in_sizes, int n_in,
                              void* d_out, int out_size, void* d_ws, size_t ws_size,
                              hipStream_t stream) {
    const int*   edge = (const int*)d_in[0];    // [2, E]: row then col
    const float* ue   = (const float*)d_in[2];
    const float* me   = (const float*)d_in[3];
    float*       out  = (float*)d_out;

    const int E        = in_sizes[0] / 2;
    const int n_users  = in_sizes[2] / EMB;
    const int n_movies = in_sizes[3] / EMB;
    const int N        = n_users + n_movies;
    const int* row = edge;
    const int* col = edge + E;
    const int nb2 = (N + BW2 - 1) >> BSH2;      // 586 coarse buckets

    // workspace layout
    char* ws = (char*)d_ws;
    auto align_up = [](size_t v) { return (v + 255) & ~(size_t)255; };
    int*    gcount = (int*)ws;    ws += align_up((size_t)NB2MAX * SUBC * GSPREAD * sizeof(int));
    int2*   sd     = (int2*)ws;   ws += align_up((size_t)N * sizeof(int2));
    float*  dis    = (float*)ws;  ws += align_up((size_t)N * sizeof(float));
    int*    tmp    = (int*)ws;    ws += align_up((size_t)nb2 * CAP * sizeof(int));
    int*    eg     = (int*)ws;    ws += align_up((size_t)nb2 * 2 * EGCAP * sizeof(int));
    half_t* sA     = (half_t*)ws; ws += align_up((size_t)(N + 1) * EMB * sizeof(half_t));
    half_t* sB     = (half_t*)ws; ws += align_up((size_t)(N + 1) * EMB * sizeof(half_t));

    // two-pass counting sort -> padded CSR (deg/dis/s0/zero-rows fused in pass 2)
    hipMemsetAsync(gcount, 0, (size_t)NB2MAX * SUBC * GSPREAD * sizeof(int), stream);
    part_kernel<<<(E + P1_BATCH - 1) / P1_BATCH, P1_TH, 0, stream>>>(
        row, col, gcount, tmp, E, nb2);
    bin_kernel<<<2 * nb2, BINTH, 0, stream>>>(
        tmp, gcount, eg, sd, dis,
        (const float4*)ue, (const float4*)me, (uint2*)sA, (uint2*)sB,
        n_users, N);

    // 3 propagation layers (atomic-free pull, packed fp16; s-tables only)
    const int waves_per_block = 4;   // 256 threads
    const int gblocks = (N + waves_per_block - 1) / waves_per_block;
    gather_kernel<1><<<gblocks, 256, 0, stream>>>(
        eg, sd, dis, (const uint4*)sA, (uint2*)sB,
        nullptr, nullptr, nullptr, nullptr, nullptr, n_users, N);
    gather_kernel<2><<<gblocks, 256, 0, stream>>>(
        eg, sd, dis, (const uint4*)sB, (uint2*)sA,
        nullptr, nullptr, nullptr, nullptr, nullptr, n_users, N);
    gather_kernel<3><<<gblocks, 256, 0, stream>>>(
        eg, sd, dis, (const uint4*)sA, nullptr,
        (const uint2*)sB, (const uint2*)sA,
        (const float4*)ue, (const float4*)me, (float4*)out, n_users, N);
}